// Round 1
// baseline (895.374 us; speedup 1.0000x reference)
//
#include <hip/hip_runtime.h>
#include <hip/hip_bf16.h>
#include <cstdint>
#include <cstddef>

// ---------- types ----------
typedef __attribute__((ext_vector_type(4))) float f32x4;
typedef __attribute__((ext_vector_type(8))) short bf16x8;   // 8 bf16 in 4 VGPRs (guide §3)

#define E_  6
#define B_  8192
#define H_  512

// ---------- bf16 split helpers ----------
__device__ __forceinline__ unsigned short f32_to_bf16_rn(float f) {
    uint32_t u = __float_as_uint(f);
    uint32_t r = (u + 0x7fffu + ((u >> 16) & 1u)) >> 16;   // round-to-nearest-even
    return (unsigned short)r;
}
__device__ __forceinline__ float bf16_to_f32(unsigned short h) {
    return __uint_as_float(((uint32_t)h) << 16);
}

// =====================================================================
// convert_h: f32 activations (optionally concat of two tensors) ->
// fragment-major hi/lo bf16 layout:
//   chunk c = ((bm*NK + kstep)*8 + mfrag)*64 + lane   (16 B per chunk-lane)
//   element: b = bm*128 + mfrag*16 + (lane&15),  k = kstep*32 + (lane>>4)*8 + j
// =====================================================================
__global__ void convert_h_kernel(const float* __restrict__ srcA, const float* __restrict__ srcB,
                                 int splitA, int K_in, int NK, int nchunks,
                                 short* __restrict__ dhi, short* __restrict__ dlo)
{
    int c = blockIdx.x * 256 + threadIdx.x;
    if (c >= nchunks) return;
    int lane  = c & 63;
    int mf    = (c >> 6) & 7;
    int rest  = c >> 9;
    int kstep = rest % NK;
    int bm    = rest / NK;
    int b  = bm * 128 + mf * 16 + (lane & 15);
    int k0 = kstep * 32 + (lane >> 4) * 8;

    union { short s[8]; int4 v; } uh, ul;
#pragma unroll
    for (int j = 0; j < 8; ++j) {
        int k = k0 + j;
        float v = 0.f;
        if (k < K_in) {
            v = (k < splitA) ? srcA[(size_t)b * splitA + k]
                             : srcB[(size_t)b * (K_in - splitA) + (k - splitA)];
        }
        unsigned short h = f32_to_bf16_rn(v);
        float rem = v - bf16_to_f32(h);
        unsigned short l = f32_to_bf16_rn(rem);
        uh.s[j] = (short)h;
        ul.s[j] = (short)l;
    }
    *reinterpret_cast<int4*>(dhi + (size_t)c * 8) = uh.v;
    *reinterpret_cast<int4*>(dlo + (size_t)c * 8) = ul.v;
}

// =====================================================================
// convert_w: w [E, K_in, 512] f32 -> fragment-major hi/lo bf16:
//   chunk c = (((e*8 + bn)*NK + kstep)*4 + nfrag)*64 + lane
//   element: o = bn*64 + nfrag*16 + (lane&15), k = kstep*32 + (lane>>4)*8 + j
// =====================================================================
__global__ void convert_w_kernel(const float* __restrict__ w, int K_in, int NK, int nchunks,
                                 short* __restrict__ dhi, short* __restrict__ dlo)
{
    int c = blockIdx.x * 256 + threadIdx.x;
    if (c >= nchunks) return;
    int lane  = c & 63;
    int nf    = (c >> 6) & 3;
    int rest  = c >> 8;
    int kstep = rest % NK;
    int eb    = rest / NK;
    int bn    = eb & 7;
    int e     = eb >> 3;
    int o  = bn * 64 + nf * 16 + (lane & 15);
    int k0 = kstep * 32 + (lane >> 4) * 8;

    union { short s[8]; int4 v; } uh, ul;
#pragma unroll
    for (int j = 0; j < 8; ++j) {
        int k = k0 + j;
        float v = 0.f;
        if (k < K_in) v = w[((size_t)e * K_in + k) * H_ + o];
        unsigned short h = f32_to_bf16_rn(v);
        float rem = v - bf16_to_f32(h);
        unsigned short l = f32_to_bf16_rn(rem);
        uh.s[j] = (short)h;
        ul.s[j] = (short)l;
    }
    *reinterpret_cast<int4*>(dhi + (size_t)c * 8) = uh.v;
    *reinterpret_cast<int4*>(dlo + (size_t)c * 8) = ul.v;
}

// =====================================================================
// blend_gemm: out[b,o] = elu( sum_e coef[b,e]*(sum_k A[b,k] W_e[k,o]) + sum_e coef[b,e]*bias[e,o] )
// BM=128, BN=64, BK=32, 256 threads = 4 waves, wave tile 64x32 (4x2 frags of 16x16).
// 3-pass bf16 hi/lo split MFMA. A/B staged via global_load_lds (16B) into
// lane-linear LDS chunks (conflict-free b128 reads).
// =====================================================================
__global__ __launch_bounds__(256, 2)
void blend_gemm_kernel(const short* __restrict__ Ah, const short* __restrict__ Al,
                       const short* __restrict__ Bh, const short* __restrict__ Bl,
                       const float* __restrict__ coef, const float* __restrict__ bias,
                       float* __restrict__ out, int NK)
{
    // 24 chunks x 512 shorts = 24 KB: [0..7]=Ah mf, [8..15]=Al, [16..19]=Bh nf, [20..23]=Bl
    __shared__ __align__(16) short lds[24 * 512];

    const int tid  = threadIdx.x;
    const int lane = tid & 63;
    const int wave = tid >> 6;
    const int wm   = wave >> 1;   // 0..1
    const int wn   = wave & 1;    // 0..1
    const int bn   = blockIdx.x;  // 0..7
    const int bm   = blockIdx.y;  // 0..63

    const size_t abase     = (size_t)bm * NK * 4096;   // shorts: NK*8*512 per bm strip
    const size_t bstride_e = (size_t)8 * NK * 2048;    // shorts per expert
    const size_t bbase0    = (size_t)bn * NK * 2048;

    const f32x4 zero = {0.f, 0.f, 0.f, 0.f};
    f32x4 acc_t[4][2];
#pragma unroll
    for (int mf = 0; mf < 4; ++mf)
#pragma unroll
        for (int nf = 0; nf < 2; ++nf) acc_t[mf][nf] = zero;

    for (int e = 0; e < E_; ++e) {
        f32x4 acc_e[4][2];
#pragma unroll
        for (int mf = 0; mf < 4; ++mf)
#pragma unroll
            for (int nf = 0; nf < 2; ++nf) acc_e[mf][nf] = zero;

        const size_t bbase = (size_t)e * bstride_e + bbase0;

        for (int s = 0; s < NK; ++s) {
            const size_t a_s = abase + (size_t)s * 4096;
            const size_t b_s = bbase + (size_t)s * 2048;
#pragma unroll
            for (int c0 = 0; c0 < 6; ++c0) {
                int ch = wave * 6 + c0;
                const short* g;
                if (ch < 8)       g = Ah + a_s + ch * 512;
                else if (ch < 16) g = Al + a_s + (ch - 8) * 512;
                else if (ch < 20) g = Bh + b_s + (ch - 16) * 512;
                else              g = Bl + b_s + (ch - 20) * 512;
                __builtin_amdgcn_global_load_lds(
                    (const __attribute__((address_space(1))) short*)(g + lane * 8),
                    (__attribute__((address_space(3))) short*)(&lds[ch * 512]),
                    16, 0, 0);
            }
            __syncthreads();   // compiler emits vmcnt(0) drain before s_barrier

            bf16x8 ah[4], al4[4], bh[2], bl[2];
#pragma unroll
            for (int mf = 0; mf < 4; ++mf) {
                ah[mf]  = *reinterpret_cast<const bf16x8*>(&lds[((wm * 4 + mf) * 64 + lane) * 8]);
                al4[mf] = *reinterpret_cast<const bf16x8*>(&lds[((8 + wm * 4 + mf) * 64 + lane) * 8]);
            }
#pragma unroll
            for (int nf = 0; nf < 2; ++nf) {
                bh[nf] = *reinterpret_cast<const bf16x8*>(&lds[((16 + wn * 2 + nf) * 64 + lane) * 8]);
                bl[nf] = *reinterpret_cast<const bf16x8*>(&lds[((20 + wn * 2 + nf) * 64 + lane) * 8]);
            }
#pragma unroll
            for (int mf = 0; mf < 4; ++mf)
#pragma unroll
                for (int nf = 0; nf < 2; ++nf) {
                    acc_e[mf][nf] = __builtin_amdgcn_mfma_f32_16x16x32_bf16(ah[mf],  bh[nf], acc_e[mf][nf], 0, 0, 0);
                    acc_e[mf][nf] = __builtin_amdgcn_mfma_f32_16x16x32_bf16(ah[mf],  bl[nf], acc_e[mf][nf], 0, 0, 0);
                    acc_e[mf][nf] = __builtin_amdgcn_mfma_f32_16x16x32_bf16(al4[mf], bh[nf], acc_e[mf][nf], 0, 0, 0);
                }
            __syncthreads();   // protect LDS before next stage
        }

        // blend acc_e into acc_t with per-row coef  (C layout: col=lane&15, row=(lane>>4)*4+reg)
#pragma unroll
        for (int mf = 0; mf < 4; ++mf) {
            const int r0 = bm * 128 + wm * 64 + mf * 16 + (lane >> 4) * 4;
            float c0 = coef[(size_t)(r0 + 0) * E_ + e];
            float c1 = coef[(size_t)(r0 + 1) * E_ + e];
            float c2 = coef[(size_t)(r0 + 2) * E_ + e];
            float c3 = coef[(size_t)(r0 + 3) * E_ + e];
#pragma unroll
            for (int nf = 0; nf < 2; ++nf) {
                acc_t[mf][nf][0] += c0 * acc_e[mf][nf][0];
                acc_t[mf][nf][1] += c1 * acc_e[mf][nf][1];
                acc_t[mf][nf][2] += c2 * acc_e[mf][nf][2];
                acc_t[mf][nf][3] += c3 * acc_e[mf][nf][3];
            }
        }
    }

    // epilogue: blended bias + ELU + store f32
#pragma unroll
    for (int mf = 0; mf < 4; ++mf) {
        const int r0 = bm * 128 + wm * 64 + mf * 16 + (lane >> 4) * 4;
#pragma unroll
        for (int q = 0; q < 4; ++q) {
            const int r = r0 + q;
            float cf[E_];
#pragma unroll
            for (int e2 = 0; e2 < E_; ++e2) cf[e2] = coef[(size_t)r * E_ + e2];
#pragma unroll
            for (int nf = 0; nf < 2; ++nf) {
                const int col = bn * 64 + wn * 32 + nf * 16 + (lane & 15);
                float v = acc_t[mf][nf][q];
#pragma unroll
                for (int e2 = 0; e2 < E_; ++e2) v += cf[e2] * bias[e2 * H_ + col];
                v = v > 0.f ? v : expm1f(v);
                out[(size_t)r * H_ + col] = v;
            }
        }
    }
}

// =====================================================================
// host launcher
// =====================================================================
extern "C" void kernel_launch(void* const* d_in, const int* in_sizes, int n_in,
                              void* d_out, int out_size, void* d_ws, size_t ws_size,
                              hipStream_t stream)
{
    if (n_in < 9) return;
    const float* frame = (const float*)d_in[0];   // [8192,1830]
    const float* Iin   = (const float*)d_in[1];   // [8192,256]
    const float* coef  = (const float*)d_in[2];   // [8192,6]
    const float* w1    = (const float*)d_in[3];   // [6,2086,512]
    const float* b1    = (const float*)d_in[4];   // [6,512]
    const float* w2    = (const float*)d_in[5];   // [6,512,512]
    const float* b2    = (const float*)d_in[6];
    const float* w3    = (const float*)d_in[7];
    const float* b3    = (const float*)d_in[8];
    float* out = (float*)d_out;
    char* ws = (char*)d_ws;

    const int NK1 = 66;   // ceil(2086/32) -> K padded to 2112
    const int NK2 = 16;   // 512/32

    const size_t A0sz = (size_t)8192 * 2112 * 2;     // 34,603,008 B per copy
    const size_t W1sz = (size_t)6 * 2112 * 512 * 2;  // 12,976,128
    const size_t W2sz = (size_t)6 * 512 * 512 * 2;   //  3,145,728
    const size_t H1f  = (size_t)8192 * 512 * 4;      // 16,777,216
    const size_t H1b  = (size_t)8192 * 512 * 2;      //  8,388,608

    const size_t need = 2 * A0sz + 2 * W1sz + 4 * W2sz + H1f + 2 * H1b; // ~141.3 MB
    if (ws_size < need) return;

    short* A0h = (short*)(ws);
    short* A0l = (short*)(ws + A0sz);
    short* w1h = (short*)(ws + 2 * A0sz);
    short* w1l = (short*)(ws + 2 * A0sz + W1sz);
    short* w2h = (short*)(ws + 2 * A0sz + 2 * W1sz);
    short* w2l = (short*)(ws + 2 * A0sz + 2 * W1sz + W2sz);
    short* w3h = (short*)(ws + 2 * A0sz + 2 * W1sz + 2 * W2sz);
    short* w3l = (short*)(ws + 2 * A0sz + 2 * W1sz + 3 * W2sz);
    float* h1  = (float*)(ws + 2 * A0sz + 2 * W1sz + 4 * W2sz);
    short* h1h = (short*)((char*)h1 + H1f);
    short* h1l = (short*)((char*)h1 + H1f + H1b);
    // A0 region is dead after GEMM1 -> reuse it for layer-2 outputs
    float* h2  = (float*)(ws);
    short* h2h = (short*)(ws + H1f);
    short* h2l = (short*)(ws + H1f + H1b);

    // prep: fragment-major hi/lo conversions
    {
        int nch = (8192 / 128) * NK1 * 8 * 64;   // 2,162,688
        convert_h_kernel<<<nch / 256, 256, 0, stream>>>(frame, Iin, 1830, 2086, NK1, nch, A0h, A0l);
    }
    {
        int nch = 6 * 8 * NK1 * 4 * 64;          // 811,008
        convert_w_kernel<<<nch / 256, 256, 0, stream>>>(w1, 2086, NK1, nch, w1h, w1l);
    }
    {
        int nch = 6 * 8 * NK2 * 4 * 64;          // 196,608
        convert_w_kernel<<<nch / 256, 256, 0, stream>>>(w2, 512, NK2, nch, w2h, w2l);
        convert_w_kernel<<<nch / 256, 256, 0, stream>>>(w3, 512, NK2, nch, w3h, w3l);
    }

    dim3 gg(8, 64);   // (bn, bm)
    // layer 1
    blend_gemm_kernel<<<gg, 256, 0, stream>>>(A0h, A0l, w1h, w1l, coef, b1, h1, NK1);
    {
        int nch = (8192 / 128) * NK2 * 8 * 64;   // 524,288
        convert_h_kernel<<<nch / 256, 256, 0, stream>>>(h1, nullptr, 512, 512, NK2, nch, h1h, h1l);
    }
    // layer 2
    blend_gemm_kernel<<<gg, 256, 0, stream>>>(h1h, h1l, w2h, w2l, coef, b2, h2, NK2);
    {
        int nch = (8192 / 128) * NK2 * 8 * 64;
        convert_h_kernel<<<nch / 256, 256, 0, stream>>>(h2, nullptr, 512, 512, NK2, nch, h2h, h2l);
    }
    // layer 3 -> final output
    blend_gemm_kernel<<<gg, 256, 0, stream>>>(h2h, h2l, w3h, w3l, coef, b3, out, NK2);
}

// Round 2
// 781.732 us; speedup vs baseline: 1.1454x; 1.1454x over previous
//
#include <hip/hip_runtime.h>
#include <hip/hip_bf16.h>
#include <cstdint>
#include <cstddef>

// ---------- types ----------
typedef __attribute__((ext_vector_type(4))) float f32x4;
typedef __attribute__((ext_vector_type(8))) short bf16x8;   // 8 bf16 in 4 VGPRs

#define E_  6
#define B_  8192
#define H_  512

// ---------- bf16 split helpers ----------
__device__ __forceinline__ unsigned short f32_to_bf16_rn(float f) {
    uint32_t u = __float_as_uint(f);
    uint32_t r = (u + 0x7fffu + ((u >> 16) & 1u)) >> 16;   // round-to-nearest-even
    return (unsigned short)r;
}
__device__ __forceinline__ float bf16_to_f32(unsigned short h) {
    return __uint_as_float(((uint32_t)h) << 16);
}

// =====================================================================
// convert_h: f32 activations (optionally concat of two tensors) ->
// fragment-major hi/lo bf16 layout:
//   chunk c = ((bm*NK + kstep)*8 + mfrag)*64 + lane   (16 B per chunk-lane)
//   element: b = bm*128 + mfrag*16 + (lane&15),  k = kstep*32 + (lane>>4)*8 + j
// =====================================================================
__global__ void convert_h_kernel(const float* __restrict__ srcA, const float* __restrict__ srcB,
                                 int splitA, int K_in, int NK, int nchunks,
                                 short* __restrict__ dhi, short* __restrict__ dlo)
{
    int c = blockIdx.x * 256 + threadIdx.x;
    if (c >= nchunks) return;
    int lane  = c & 63;
    int mf    = (c >> 6) & 7;
    int rest  = c >> 9;
    int kstep = rest % NK;
    int bm    = rest / NK;
    int b  = bm * 128 + mf * 16 + (lane & 15);
    int k0 = kstep * 32 + (lane >> 4) * 8;

    union { short s[8]; int4 v; } uh, ul;
#pragma unroll
    for (int j = 0; j < 8; ++j) {
        int k = k0 + j;
        float v = 0.f;
        if (k < K_in) {
            v = (k < splitA) ? srcA[(size_t)b * splitA + k]
                             : srcB[(size_t)b * (K_in - splitA) + (k - splitA)];
        }
        unsigned short h = f32_to_bf16_rn(v);
        float rem = v - bf16_to_f32(h);
        unsigned short l = f32_to_bf16_rn(rem);
        uh.s[j] = (short)h;
        ul.s[j] = (short)l;
    }
    *reinterpret_cast<int4*>(dhi + (size_t)c * 8) = uh.v;
    *reinterpret_cast<int4*>(dlo + (size_t)c * 8) = ul.v;
}

// =====================================================================
// convert_w: w [E, K_in, 512] f32 -> fragment-major hi/lo bf16:
//   chunk c = (((e*8 + bn)*NK + kstep)*4 + nfrag)*64 + lane
//   element: o = bn*64 + nfrag*16 + (lane&15), k = kstep*32 + (lane>>4)*8 + j
// =====================================================================
__global__ void convert_w_kernel(const float* __restrict__ w, int K_in, int NK, int nchunks,
                                 short* __restrict__ dhi, short* __restrict__ dlo)
{
    int c = blockIdx.x * 256 + threadIdx.x;
    if (c >= nchunks) return;
    int lane  = c & 63;
    int nf    = (c >> 6) & 3;
    int rest  = c >> 8;
    int kstep = rest % NK;
    int eb    = rest / NK;
    int bn    = eb & 7;
    int e     = eb >> 3;
    int o  = bn * 64 + nf * 16 + (lane & 15);
    int k0 = kstep * 32 + (lane >> 4) * 8;

    union { short s[8]; int4 v; } uh, ul;
#pragma unroll
    for (int j = 0; j < 8; ++j) {
        int k = k0 + j;
        float v = 0.f;
        if (k < K_in) v = w[((size_t)e * K_in + k) * H_ + o];
        unsigned short h = f32_to_bf16_rn(v);
        float rem = v - bf16_to_f32(h);
        unsigned short l = f32_to_bf16_rn(rem);
        uh.s[j] = (short)h;
        ul.s[j] = (short)l;
    }
    *reinterpret_cast<int4*>(dhi + (size_t)c * 8) = uh.v;
    *reinterpret_cast<int4*>(dlo + (size_t)c * 8) = ul.v;
}

// =====================================================================
// blend_gemm v2:
//   out[b,o] = elu( sum_e coef[b,e]*(sum_k A[b,k] W_e[k,o] + bias[e,o]) )
// BM=128, BN=64, BK=32, 256 threads = 4 waves, wave tile 64x32 (4x2 frags).
// Per k-step: stage A(hi+lo, 16 chunks) + B of ALL 6 experts (48 chunks)
// = 64 KB LDS, ONE barrier pair, 144 MFMA between barriers.
// 6 per-expert accumulators (192 VGPRs); blend+bias+ELU in epilogue.
// Block mapping: bn = blk & 7 -> same-bn blocks land on one XCD
// (round-robin default) so the 3.24 MB weight slice stays L2-resident.
// =====================================================================
__global__ __launch_bounds__(256, 2)
void blend_gemm_kernel(const short* __restrict__ Ah, const short* __restrict__ Al,
                       const short* __restrict__ Bh, const short* __restrict__ Bl,
                       const float* __restrict__ coef, const float* __restrict__ bias,
                       float* __restrict__ out, int NK)
{
    // 64 chunks x 512 shorts = 64 KB:
    //   [0..7]   A hi (mf),  [8..15]  A lo (mf)
    //   [16+e*8+t] : t=0..3 B hi (nf), t=4..7 B lo (nf)
    __shared__ __align__(16) short lds[64 * 512];

    const int tid  = threadIdx.x;
    const int lane = tid & 63;
    const int wave = tid >> 6;
    const int wm   = wave >> 1;   // 0..1
    const int wn   = wave & 1;    // 0..1
    const int blk  = blockIdx.x;
    const int bn   = blk & 7;     // XCD-pinned weight slice
    const int bm   = blk >> 3;    // 0..63

    const size_t abase     = (size_t)bm * NK * 4096;   // shorts
    const size_t bstride_e = (size_t)8 * NK * 2048;    // shorts per expert
    const size_t bbase0    = (size_t)bn * NK * 2048;

    const f32x4 zero = {0.f, 0.f, 0.f, 0.f};
    f32x4 acc[E_][4][2];
#pragma unroll
    for (int e = 0; e < E_; ++e)
#pragma unroll
        for (int mf = 0; mf < 4; ++mf)
#pragma unroll
            for (int nf = 0; nf < 2; ++nf) acc[e][mf][nf] = zero;

    for (int s = 0; s < NK; ++s) {
        const size_t a_s = abase + (size_t)s * 4096;
        const size_t b_s = bbase0 + (size_t)s * 2048;

        // ---- stage: 16 chunks per wave ----
#pragma unroll
        for (int i = 0; i < 16; ++i) {
            const int ch = wave * 16 + i;
            const short* g;
            if (ch < 8)        g = Ah + a_s + ch * 512;
            else if (ch < 16)  g = Al + a_s + (ch - 8) * 512;
            else {
                const int cc = ch - 16;
                const int e  = cc >> 3;
                const int t  = cc & 7;
                const size_t off = (size_t)e * bstride_e + b_s + (size_t)(t & 3) * 512;
                g = ((t < 4) ? Bh : Bl) + off;
            }
            __builtin_amdgcn_global_load_lds(
                (const __attribute__((address_space(1))) short*)(g + lane * 8),
                (__attribute__((address_space(3))) short*)(&lds[ch * 512]),
                16, 0, 0);
        }
        __syncthreads();   // vmcnt(0) drain + barrier

        // ---- compute: A frags once, loop experts ----
        bf16x8 ah[4], al4[4];
#pragma unroll
        for (int mf = 0; mf < 4; ++mf) {
            ah[mf]  = *reinterpret_cast<const bf16x8*>(&lds[((wm * 4 + mf) * 64 + lane) * 8]);
            al4[mf] = *reinterpret_cast<const bf16x8*>(&lds[((8 + wm * 4 + mf) * 64 + lane) * 8]);
        }
#pragma unroll
        for (int e = 0; e < E_; ++e) {
            bf16x8 bh[2], bl[2];
#pragma unroll
            for (int nf = 0; nf < 2; ++nf) {
                bh[nf] = *reinterpret_cast<const bf16x8*>(&lds[((16 + e * 8 +     wn * 2 + nf) * 64 + lane) * 8]);
                bl[nf] = *reinterpret_cast<const bf16x8*>(&lds[((16 + e * 8 + 4 + wn * 2 + nf) * 64 + lane) * 8]);
            }
#pragma unroll
            for (int mf = 0; mf < 4; ++mf)
#pragma unroll
                for (int nf = 0; nf < 2; ++nf) {
                    acc[e][mf][nf] = __builtin_amdgcn_mfma_f32_16x16x32_bf16(ah[mf],  bh[nf], acc[e][mf][nf], 0, 0, 0);
                    acc[e][mf][nf] = __builtin_amdgcn_mfma_f32_16x16x32_bf16(ah[mf],  bl[nf], acc[e][mf][nf], 0, 0, 0);
                    acc[e][mf][nf] = __builtin_amdgcn_mfma_f32_16x16x32_bf16(al4[mf], bh[nf], acc[e][mf][nf], 0, 0, 0);
                }
        }
        __syncthreads();   // protect LDS before next stage
    }

    // ---- epilogue: blend + bias + ELU + store ----
    // bias values per thread's two columns, hoisted (12 loads)
    float bb[E_][2];
#pragma unroll
    for (int nf = 0; nf < 2; ++nf) {
        const int col = bn * 64 + wn * 32 + nf * 16 + (lane & 15);
#pragma unroll
        for (int e = 0; e < E_; ++e) bb[e][nf] = bias[e * H_ + col];
    }

#pragma unroll
    for (int mf = 0; mf < 4; ++mf) {
        const int r0 = bm * 128 + wm * 64 + mf * 16 + (lane >> 4) * 4;
#pragma unroll
        for (int q = 0; q < 4; ++q) {
            const int r = r0 + q;
            const float2* c2 = reinterpret_cast<const float2*>(coef + (size_t)r * E_);
            float2 ca = c2[0], cb = c2[1], cc = c2[2];
            float cf[E_] = {ca.x, ca.y, cb.x, cb.y, cc.x, cc.y};
#pragma unroll
            for (int nf = 0; nf < 2; ++nf) {
                const int col = bn * 64 + wn * 32 + nf * 16 + (lane & 15);
                float v = 0.f;
#pragma unroll
                for (int e = 0; e < E_; ++e)
                    v += cf[e] * (acc[e][mf][nf][q] + bb[e][nf]);
                v = v > 0.f ? v : expm1f(v);
                out[(size_t)r * H_ + col] = v;
            }
        }
    }
}

// =====================================================================
// host launcher
// =====================================================================
extern "C" void kernel_launch(void* const* d_in, const int* in_sizes, int n_in,
                              void* d_out, int out_size, void* d_ws, size_t ws_size,
                              hipStream_t stream)
{
    if (n_in < 9) return;
    const float* frame = (const float*)d_in[0];   // [8192,1830]
    const float* Iin   = (const float*)d_in[1];   // [8192,256]
    const float* coef  = (const float*)d_in[2];   // [8192,6]
    const float* w1    = (const float*)d_in[3];   // [6,2086,512]
    const float* b1    = (const float*)d_in[4];   // [6,512]
    const float* w2    = (const float*)d_in[5];   // [6,512,512]
    const float* b2    = (const float*)d_in[6];
    const float* w3    = (const float*)d_in[7];
    const float* b3    = (const float*)d_in[8];
    float* out = (float*)d_out;
    char* ws = (char*)d_ws;

    const int NK1 = 66;   // ceil(2086/32) -> K padded to 2112
    const int NK2 = 16;   // 512/32

    const size_t A0sz = (size_t)8192 * 2112 * 2;     // bytes per copy
    const size_t W1sz = (size_t)6 * 2112 * 512 * 2;
    const size_t W2sz = (size_t)6 * 512 * 512 * 2;
    const size_t H1f  = (size_t)8192 * 512 * 4;
    const size_t H1b  = (size_t)8192 * 512 * 2;

    const size_t need = 2 * A0sz + 2 * W1sz + 4 * W2sz + H1f + 2 * H1b;
    if (ws_size < need) return;

    short* A0h = (short*)(ws);
    short* A0l = (short*)(ws + A0sz);
    short* w1h = (short*)(ws + 2 * A0sz);
    short* w1l = (short*)(ws + 2 * A0sz + W1sz);
    short* w2h = (short*)(ws + 2 * A0sz + 2 * W1sz);
    short* w2l = (short*)(ws + 2 * A0sz + 2 * W1sz + W2sz);
    short* w3h = (short*)(ws + 2 * A0sz + 2 * W1sz + 2 * W2sz);
    short* w3l = (short*)(ws + 2 * A0sz + 2 * W1sz + 3 * W2sz);
    float* h1  = (float*)(ws + 2 * A0sz + 2 * W1sz + 4 * W2sz);
    short* h1h = (short*)((char*)h1 + H1f);
    short* h1l = (short*)((char*)h1 + H1f + H1b);
    // A0 region dead after GEMM1 -> reuse for layer-2 outputs
    float* h2  = (float*)(ws);
    short* h2h = (short*)(ws + H1f);
    short* h2l = (short*)(ws + H1f + H1b);

    // prep: fragment-major hi/lo conversions
    {
        int nch = (8192 / 128) * NK1 * 8 * 64;
        convert_h_kernel<<<nch / 256, 256, 0, stream>>>(frame, Iin, 1830, 2086, NK1, nch, A0h, A0l);
    }
    {
        int nch = 6 * 8 * NK1 * 4 * 64;
        convert_w_kernel<<<nch / 256, 256, 0, stream>>>(w1, 2086, NK1, nch, w1h, w1l);
    }
    {
        int nch = 6 * 8 * NK2 * 4 * 64;
        convert_w_kernel<<<nch / 256, 256, 0, stream>>>(w2, 512, NK2, nch, w2h, w2l);
        convert_w_kernel<<<nch / 256, 256, 0, stream>>>(w3, 512, NK2, nch, w3h, w3l);
    }

    const int grid = 512;   // 64 bm x 8 bn, bn = blk & 7 (XCD-pinned)
    // layer 1
    blend_gemm_kernel<<<grid, 256, 0, stream>>>(A0h, A0l, w1h, w1l, coef, b1, h1, NK1);
    {
        int nch = (8192 / 128) * NK2 * 8 * 64;
        convert_h_kernel<<<nch / 256, 256, 0, stream>>>(h1, nullptr, 512, 512, NK2, nch, h1h, h1l);
    }
    // layer 2
    blend_gemm_kernel<<<grid, 256, 0, stream>>>(h1h, h1l, w2h, w2l, coef, b2, h2, NK2);
    {
        int nch = (8192 / 128) * NK2 * 8 * 64;
        convert_h_kernel<<<nch / 256, 256, 0, stream>>>(h2, nullptr, 512, 512, NK2, nch, h2h, h2l);
    }
    // layer 3 -> final output
    blend_gemm_kernel<<<grid, 256, 0, stream>>>(h2h, h2l, w3h, w3l, coef, b3, out, NK2);
}

// Round 3
// 602.109 us; speedup vs baseline: 1.4871x; 1.2983x over previous
//
#include <hip/hip_runtime.h>
#include <hip/hip_bf16.h>
#include <cstdint>
#include <cstddef>

// ---------- types ----------
typedef __attribute__((ext_vector_type(4))) float f32x4;
typedef __attribute__((ext_vector_type(8))) short bf16x8;   // 8 bf16 in 4 VGPRs

#define E_  6
#define B_  8192
#define H_  512

// ---------- bf16 split helpers ----------
__device__ __forceinline__ unsigned short f32_to_bf16_rn(float f) {
    uint32_t u = __float_as_uint(f);
    uint32_t r = (u + 0x7fffu + ((u >> 16) & 1u)) >> 16;   // round-to-nearest-even
    return (unsigned short)r;
}
__device__ __forceinline__ float bf16_to_f32(unsigned short h) {
    return __uint_as_float(((uint32_t)h) << 16);
}

// =====================================================================
// convert_h: f32 activations (optionally concat of two tensors) ->
// fragment-major hi/lo bf16 layout:
//   chunk c = ((bm*NK + kstep)*8 + mfrag)*64 + lane   (16 B per chunk-lane)
//   element: b = bm*128 + mfrag*16 + (lane&15),  k = kstep*32 + (lane>>4)*8 + j
// =====================================================================
__global__ void convert_h_kernel(const float* __restrict__ srcA, const float* __restrict__ srcB,
                                 int splitA, int K_in, int NK, int nchunks,
                                 short* __restrict__ dhi, short* __restrict__ dlo)
{
    int c = blockIdx.x * 256 + threadIdx.x;
    if (c >= nchunks) return;
    int lane  = c & 63;
    int mf    = (c >> 6) & 7;
    int rest  = c >> 9;
    int kstep = rest % NK;
    int bm    = rest / NK;
    int b  = bm * 128 + mf * 16 + (lane & 15);
    int k0 = kstep * 32 + (lane >> 4) * 8;

    union { short s[8]; int4 v; } uh, ul;
#pragma unroll
    for (int j = 0; j < 8; ++j) {
        int k = k0 + j;
        float v = 0.f;
        if (k < K_in) {
            v = (k < splitA) ? srcA[(size_t)b * splitA + k]
                             : srcB[(size_t)b * (K_in - splitA) + (k - splitA)];
        }
        unsigned short h = f32_to_bf16_rn(v);
        float rem = v - bf16_to_f32(h);
        unsigned short l = f32_to_bf16_rn(rem);
        uh.s[j] = (short)h;
        ul.s[j] = (short)l;
    }
    *reinterpret_cast<int4*>(dhi + (size_t)c * 8) = uh.v;
    *reinterpret_cast<int4*>(dlo + (size_t)c * 8) = ul.v;
}

// =====================================================================
// convert_w: w [E, K_in, 512] f32 -> fragment-major hi/lo bf16:
//   chunk c = (((e*8 + bn)*NK + kstep)*4 + nfrag)*64 + lane
//   element: o = bn*64 + nfrag*16 + (lane&15), k = kstep*32 + (lane>>4)*8 + j
// =====================================================================
__global__ void convert_w_kernel(const float* __restrict__ w, int K_in, int NK, int nchunks,
                                 short* __restrict__ dhi, short* __restrict__ dlo)
{
    int c = blockIdx.x * 256 + threadIdx.x;
    if (c >= nchunks) return;
    int lane  = c & 63;
    int nf    = (c >> 6) & 3;
    int rest  = c >> 8;
    int kstep = rest % NK;
    int eb    = rest / NK;
    int bn    = eb & 7;
    int e     = eb >> 3;
    int o  = bn * 64 + nf * 16 + (lane & 15);
    int k0 = kstep * 32 + (lane >> 4) * 8;

    union { short s[8]; int4 v; } uh, ul;
#pragma unroll
    for (int j = 0; j < 8; ++j) {
        int k = k0 + j;
        float v = 0.f;
        if (k < K_in) v = w[((size_t)e * K_in + k) * H_ + o];
        unsigned short h = f32_to_bf16_rn(v);
        float rem = v - bf16_to_f32(h);
        unsigned short l = f32_to_bf16_rn(rem);
        uh.s[j] = (short)h;
        ul.s[j] = (short)l;
    }
    *reinterpret_cast<int4*>(dhi + (size_t)c * 8) = uh.v;
    *reinterpret_cast<int4*>(dlo + (size_t)c * 8) = ul.v;
}

// =====================================================================
// blend_gemm v3 — 6-phase counted-vmcnt pipeline (T3+T4+T5):
//   out[b,o] = elu( sum_e coef[b,e]*(sum_k A[b,k] W_e[k,o] + bias[e,o]) )
// BM=128, BN=64, BK=32, 256 threads = 4 waves, wave tile 64x32 (4x2 frags).
// Per k-step s: 6 phases (one expert each). A hi/lo double-buffered per s
// (2 x 16 KB), B double-buffered per phase (2 x 8 KB) -> 48 KB LDS.
// Per phase: issue next prefetch -> counted vmcnt (never 0 in steady state)
// -> s_barrier -> ds_read frags (A only at e==0, held in regs) ->
// setprio(1) 24 MFMA setprio(0) -> s_barrier.
// vmcnt audit (per wave): issues are 2 B-loads/phase, +4 A-loads at e==4
// (issued AFTER B5 so A stays in flight through e==5's vmcnt(6)):
//   e=0..3: vmcnt(2); e=4: vmcnt(6) [B5+A]; e=5: vmcnt(6) [A+B0'].
//   tail s==NK-1: e=4: vmcnt(2); e=5: vmcnt(0).
// =====================================================================
__global__ __launch_bounds__(256, 2)
void blend_gemm_kernel(const short* __restrict__ Ah, const short* __restrict__ Al,
                       const short* __restrict__ Bh, const short* __restrict__ Bl,
                       const float* __restrict__ coef, const float* __restrict__ bias,
                       float* __restrict__ out, int NK)
{
    // LDS 48 KB: A bufs at 0 / 8192 shorts (16 chunks x 512), B bufs at
    // 16384 + {0,4096} shorts (8 chunks x 512).
    __shared__ __align__(16) short lds[24576];

    const int tid  = threadIdx.x;
    const int lane = tid & 63;
    const int wave = tid >> 6;
    const int wm   = wave >> 1;   // 0..1
    const int wn   = wave & 1;    // 0..1
    const int blk  = blockIdx.x;
    const int bn   = blk & 7;     // XCD-pinned weight slice
    const int bm   = blk >> 3;    // 0..63

    const size_t abase     = (size_t)bm * NK * 4096;   // shorts (per hi/lo array)
    const size_t bstride_e = (size_t)8 * NK * 2048;    // shorts per expert
    const size_t bbase0    = (size_t)bn * NK * 2048;

    auto issueA = [&](int s) {
        const size_t a_s = abase + (size_t)s * 4096;
        short* dst = &lds[(s & 1) * 8192];
#pragma unroll
        for (int i = 0; i < 4; ++i) {
            const int ch = wave * 4 + i;
            const short* g = (ch < 8) ? (Ah + a_s + ch * 512)
                                      : (Al + a_s + (ch - 8) * 512);
            __builtin_amdgcn_global_load_lds(
                (const __attribute__((address_space(1))) short*)(g + lane * 8),
                (__attribute__((address_space(3))) short*)(dst + ch * 512),
                16, 0, 0);
        }
    };
    auto issueB = [&](int e, int s) {
        const size_t off = (size_t)e * bstride_e + bbase0 + (size_t)s * 2048;
        short* dst = &lds[16384 + (e & 1) * 4096];
#pragma unroll
        for (int i = 0; i < 2; ++i) {
            const int ch = wave * 2 + i;
            const short* g = (ch < 4) ? (Bh + off + ch * 512)
                                      : (Bl + off + (ch - 4) * 512);
            __builtin_amdgcn_global_load_lds(
                (const __attribute__((address_space(1))) short*)(g + lane * 8),
                (__attribute__((address_space(3))) short*)(dst + ch * 512),
                16, 0, 0);
        }
    };

    const f32x4 zero = {0.f, 0.f, 0.f, 0.f};
    f32x4 acc[E_][4][2];
#pragma unroll
    for (int e = 0; e < E_; ++e)
#pragma unroll
        for (int mf = 0; mf < 4; ++mf)
#pragma unroll
            for (int nf = 0; nf < 2; ++nf) acc[e][mf][nf] = zero;

    bf16x8 ah[4], al4[4];   // A frags held across the 6 phases of a k-step

    // prologue: stage k-step 0's A and expert-0 B
    issueA(0);
    issueB(0, 0);

    for (int s = 0; s < NK; ++s) {
        const bool last = (s == NK - 1);
#pragma unroll
        for (int e = 0; e < 6; ++e) {
            // ---- prefetch issue (order matters for vmcnt counting) ----
            if (e < 4) {
                issueB(e + 1, s);
            } else if (e == 4) {
                issueB(5, s);
                if (!last) issueA(s + 1);     // A issued AFTER B5
            } else {
                if (!last) issueB(0, s + 1);
            }
            // ---- counted wait + barrier ----
            if (e < 4) {
                asm volatile("s_waitcnt vmcnt(2)" ::: "memory");
            } else if (e == 4) {
                if (!last) asm volatile("s_waitcnt vmcnt(6)" ::: "memory");
                else       asm volatile("s_waitcnt vmcnt(2)" ::: "memory");
            } else {
                if (!last) asm volatile("s_waitcnt vmcnt(6)" ::: "memory");
                else       asm volatile("s_waitcnt vmcnt(0)" ::: "memory");
            }
            __builtin_amdgcn_s_barrier();
            __builtin_amdgcn_sched_barrier(0);

            // ---- fragment reads ----
            if (e == 0) {
                const short* Ab = &lds[(s & 1) * 8192];
#pragma unroll
                for (int mf = 0; mf < 4; ++mf) {
                    ah[mf]  = *reinterpret_cast<const bf16x8*>(&Ab[((wm * 4 + mf) * 64 + lane) * 8]);
                    al4[mf] = *reinterpret_cast<const bf16x8*>(&Ab[((8 + wm * 4 + mf) * 64 + lane) * 8]);
                }
            }
            const short* Bb = &lds[16384 + (e & 1) * 4096];
            bf16x8 bh[2], bl[2];
#pragma unroll
            for (int nf = 0; nf < 2; ++nf) {
                bh[nf] = *reinterpret_cast<const bf16x8*>(&Bb[((wn * 2 + nf) * 64 + lane) * 8]);
                bl[nf] = *reinterpret_cast<const bf16x8*>(&Bb[((4 + wn * 2 + nf) * 64 + lane) * 8]);
            }

            // ---- MFMA cluster ----
            __builtin_amdgcn_s_setprio(1);
#pragma unroll
            for (int mf = 0; mf < 4; ++mf)
#pragma unroll
                for (int nf = 0; nf < 2; ++nf) {
                    acc[e][mf][nf] = __builtin_amdgcn_mfma_f32_16x16x32_bf16(ah[mf],  bh[nf], acc[e][mf][nf], 0, 0, 0);
                    acc[e][mf][nf] = __builtin_amdgcn_mfma_f32_16x16x32_bf16(ah[mf],  bl[nf], acc[e][mf][nf], 0, 0, 0);
                    acc[e][mf][nf] = __builtin_amdgcn_mfma_f32_16x16x32_bf16(al4[mf], bh[nf], acc[e][mf][nf], 0, 0, 0);
                }
            __builtin_amdgcn_s_setprio(0);
            __builtin_amdgcn_sched_barrier(0);
            __builtin_amdgcn_s_barrier();
        }
    }

    // ---- epilogue: blend + bias + ELU + store ----
    float bb[E_][2];
#pragma unroll
    for (int nf = 0; nf < 2; ++nf) {
        const int col = bn * 64 + wn * 32 + nf * 16 + (lane & 15);
#pragma unroll
        for (int e = 0; e < E_; ++e) bb[e][nf] = bias[e * H_ + col];
    }

#pragma unroll
    for (int mf = 0; mf < 4; ++mf) {
        const int r0 = bm * 128 + wm * 64 + mf * 16 + (lane >> 4) * 4;
#pragma unroll
        for (int q = 0; q < 4; ++q) {
            const int r = r0 + q;
            const float2* c2 = reinterpret_cast<const float2*>(coef + (size_t)r * E_);
            float2 ca = c2[0], cb = c2[1], cc = c2[2];
            float cf[E_] = {ca.x, ca.y, cb.x, cb.y, cc.x, cc.y};
#pragma unroll
            for (int nf = 0; nf < 2; ++nf) {
                const int col = bn * 64 + wn * 32 + nf * 16 + (lane & 15);
                float v = 0.f;
#pragma unroll
                for (int e = 0; e < E_; ++e)
                    v += cf[e] * (acc[e][mf][nf][q] + bb[e][nf]);
                v = v > 0.f ? v : expm1f(v);
                out[(size_t)r * H_ + col] = v;
            }
        }
    }
}

// =====================================================================
// host launcher
// =====================================================================
extern "C" void kernel_launch(void* const* d_in, const int* in_sizes, int n_in,
                              void* d_out, int out_size, void* d_ws, size_t ws_size,
                              hipStream_t stream)
{
    if (n_in < 9) return;
    const float* frame = (const float*)d_in[0];   // [8192,1830]
    const float* Iin   = (const float*)d_in[1];   // [8192,256]
    const float* coef  = (const float*)d_in[2];   // [8192,6]
    const float* w1    = (const float*)d_in[3];   // [6,2086,512]
    const float* b1    = (const float*)d_in[4];   // [6,512]
    const float* w2    = (const float*)d_in[5];   // [6,512,512]
    const float* b2    = (const float*)d_in[6];
    const float* w3    = (const float*)d_in[7];
    const float* b3    = (const float*)d_in[8];
    float* out = (float*)d_out;
    char* ws = (char*)d_ws;

    const int NK1 = 66;   // ceil(2086/32) -> K padded to 2112
    const int NK2 = 16;   // 512/32

    const size_t A0sz = (size_t)8192 * 2112 * 2;     // bytes per copy
    const size_t W1sz = (size_t)6 * 2112 * 512 * 2;
    const size_t W2sz = (size_t)6 * 512 * 512 * 2;
    const size_t H1f  = (size_t)8192 * 512 * 4;
    const size_t H1b  = (size_t)8192 * 512 * 2;

    const size_t need = 2 * A0sz + 2 * W1sz + 4 * W2sz + H1f + 2 * H1b;
    if (ws_size < need) return;

    short* A0h = (short*)(ws);
    short* A0l = (short*)(ws + A0sz);
    short* w1h = (short*)(ws + 2 * A0sz);
    short* w1l = (short*)(ws + 2 * A0sz + W1sz);
    short* w2h = (short*)(ws + 2 * A0sz + 2 * W1sz);
    short* w2l = (short*)(ws + 2 * A0sz + 2 * W1sz + W2sz);
    short* w3h = (short*)(ws + 2 * A0sz + 2 * W1sz + 2 * W2sz);
    short* w3l = (short*)(ws + 2 * A0sz + 2 * W1sz + 3 * W2sz);
    float* h1  = (float*)(ws + 2 * A0sz + 2 * W1sz + 4 * W2sz);
    short* h1h = (short*)((char*)h1 + H1f);
    short* h1l = (short*)((char*)h1 + H1f + H1b);
    // A0 region dead after GEMM1 -> reuse for layer-2 outputs
    float* h2  = (float*)(ws);
    short* h2h = (short*)(ws + H1f);
    short* h2l = (short*)(ws + H1f + H1b);

    // prep: fragment-major hi/lo conversions
    {
        int nch = (8192 / 128) * NK1 * 8 * 64;
        convert_h_kernel<<<nch / 256, 256, 0, stream>>>(frame, Iin, 1830, 2086, NK1, nch, A0h, A0l);
    }
    {
        int nch = 6 * 8 * NK1 * 4 * 64;
        convert_w_kernel<<<nch / 256, 256, 0, stream>>>(w1, 2086, NK1, nch, w1h, w1l);
    }
    {
        int nch = 6 * 8 * NK2 * 4 * 64;
        convert_w_kernel<<<nch / 256, 256, 0, stream>>>(w2, 512, NK2, nch, w2h, w2l);
        convert_w_kernel<<<nch / 256, 256, 0, stream>>>(w3, 512, NK2, nch, w3h, w3l);
    }

    const int grid = 512;   // 64 bm x 8 bn, bn = blk & 7 (XCD-pinned)
    // layer 1
    blend_gemm_kernel<<<grid, 256, 0, stream>>>(A0h, A0l, w1h, w1l, coef, b1, h1, NK1);
    {
        int nch = (8192 / 128) * NK2 * 8 * 64;
        convert_h_kernel<<<nch / 256, 256, 0, stream>>>(h1, nullptr, 512, 512, NK2, nch, h1h, h1l);
    }
    // layer 2
    blend_gemm_kernel<<<grid, 256, 0, stream>>>(h1h, h1l, w2h, w2l, coef, b2, h2, NK2);
    {
        int nch = (8192 / 128) * NK2 * 8 * 64;
        convert_h_kernel<<<nch / 256, 256, 0, stream>>>(h2, nullptr, 512, 512, NK2, nch, h2h, h2l);
    }
    // layer 3 -> final output
    blend_gemm_kernel<<<grid, 256, 0, stream>>>(h2h, h2l, w3h, w3l, coef, b3, out, NK2);
}